// Round 8
// baseline (549.042 us; speedup 1.0000x reference)
//
#include <hip/hip_runtime.h>
#include <hip/hip_bf16.h>
#include <math.h>

typedef short short8 __attribute__((ext_vector_type(8)));
typedef float f32x4 __attribute__((ext_vector_type(4)));
typedef float f32x4u __attribute__((ext_vector_type(4), aligned(4)));

#define DEV static __device__ __forceinline__

DEV void gl2lds16(const void* g, void* l) {
  __builtin_amdgcn_global_load_lds(
      (const __attribute__((address_space(1))) unsigned int*)g,
      (__attribute__((address_space(3))) unsigned int*)l, 16, 0, 0);
}

DEV float wred_sum(float v) {
#pragma unroll
  for (int o = 1; o < 64; o <<= 1) v += __shfl_xor(v, o, 64);
  return v;
}
DEV float wred_max(float v) {
#pragma unroll
  for (int o = 1; o < 64; o <<= 1) v = fmaxf(v, __shfl_xor(v, o, 64));
  return v;
}
DEV float sigmoidf(float x) { return 1.0f / (1.0f + expf(-x)); }

DEV unsigned short f2bf(float x) {
  unsigned u = __float_as_uint(x);
  unsigned rr = (u + 0x7fffu + ((u >> 16) & 1u)) >> 16;
  return (unsigned short)rr;
}

DEV short8 cvt8(float4 f0, float4 f1) {
  union { short8 s; unsigned u[4]; } r;
  asm("v_cvt_pk_bf16_f32 %0, %1, %2" : "=v"(r.u[0]) : "v"(f0.x), "v"(f0.y));
  asm("v_cvt_pk_bf16_f32 %0, %1, %2" : "=v"(r.u[1]) : "v"(f0.z), "v"(f0.w));
  asm("v_cvt_pk_bf16_f32 %0, %1, %2" : "=v"(r.u[2]) : "v"(f1.x), "v"(f1.y));
  asm("v_cvt_pk_bf16_f32 %0, %1, %2" : "=v"(r.u[3]) : "v"(f1.z), "v"(f1.w));
  return r.s;
}

// device-scope generation barrier; all grid blocks must be co-resident (grid <= 256)
DEV void gbar(int* cnt, int* gen, int nblk) {
  __syncthreads();
  if (threadIdx.x == 0) {
    int g = __hip_atomic_load(gen, __ATOMIC_RELAXED, __HIP_MEMORY_SCOPE_AGENT);
    int prev = __hip_atomic_fetch_add(cnt, 1, __ATOMIC_ACQ_REL, __HIP_MEMORY_SCOPE_AGENT);
    if (prev == nblk - 1) {
      __hip_atomic_store(cnt, 0, __ATOMIC_RELAXED, __HIP_MEMORY_SCOPE_AGENT);
      __hip_atomic_store(gen, g + 1, __ATOMIC_RELEASE, __HIP_MEMORY_SCOPE_AGENT);
    } else {
      while (__hip_atomic_load(gen, __ATOMIC_ACQUIRE, __HIP_MEMORY_SCOPE_AGENT) == g)
        __builtin_amdgcn_s_sleep(2);
    }
  }
  __syncthreads();
}

// output layout (floats): out[50257] | h1[1024] | c1[1024] | weighted[1024] | psel[32]
#define OUT_H1 50257
#define OUT_C1 51281
#define OUT_W  52305
#define OUT_PS 53329
#define PKS 50260

// ---------------- K0 "k_prep": enc->bf16 | Wa_bot transpose->bf16 | h-matvecs | embed+barzero | nz
__global__ void k_prep(const float* __restrict__ ex, const float* __restrict__ ec,
                       const float* __restrict__ Wa, const float* __restrict__ ba,
                       const float* __restrict__ Wh, const float* __restrict__ bh,
                       const float* __restrict__ hid, const float* __restrict__ embed,
                       const int* __restrict__ idx, const float* __restrict__ pmat,
                       unsigned short* __restrict__ encb, unsigned short* __restrict__ WaT,
                       float* __restrict__ hWa, float* __restrict__ hWh,
                       float* __restrict__ yinp, float* __restrict__ nz,
                       int* __restrict__ barr) {
  int bx = blockIdx.x, t = threadIdx.x;
  if (bx < 6144) {
    size_t i = ((size_t)bx * 256 + t) * 8;
    const float* src = (i < 8388608) ? (ex + i) : (ec + (i - 8388608));
    float4 f0 = *(const float4*)src;
    float4 f1 = *(const float4*)(src + 4);
    *(short8*)&encb[i] = cvt8(f0, f1);
  } else if (bx < 6400) {
    __shared__ float tile[64][65];
    int bb = bx - 6144;
    int bi = bb >> 4, bj = bb & 15;
    int c = t & 63, rq = t >> 6;
#pragma unroll
    for (int rr = 0; rr < 16; rr++) {
      int kl = rr * 4 + rq;
      tile[kl][c] = Wa[(size_t)(1024 + bi * 64 + kl) * 1024 + bj * 64 + c];
    }
    __syncthreads();
#pragma unroll
    for (int rr = 0; rr < 16; rr++) {
      int nl = rr * 4 + rq;
      WaT[(size_t)(bj * 64 + nl) * 1024 + bi * 64 + c] = f2bf(tile[c][nl]);
    }
  } else if (bx < 6432) {
    __shared__ float red[4][64];
    int bb = bx - 6400;
    int ol = t & 63, kc = t >> 6;
    int o = bb * 64 + ol;
    const float* W = (o < 1024) ? Wa : Wh;
    int col = (o < 1024) ? o : (o - 1024);
    float acc = 0.f;
#pragma unroll 4
    for (int k = kc * 256; k < kc * 256 + 256; k++) acc += hid[k] * W[(size_t)k * 1024 + col];
    red[kc][ol] = acc;
    __syncthreads();
    if (t < 64) {
      int oo = bb * 64 + t;
      float s = red[0][t] + red[1][t] + red[2][t] + red[3][t];
      if (oo < 1024) hWa[oo] = s + ba[oo];
      else hWh[oo - 1024] = s + bh[oo - 1024];
    }
  } else if (bx == 6432) {
    if (t < 4) barr[t] = 0;  // zero barrier state every call (stateless launch)
    int id = idx[0];
    for (int k = t; k < 300; k += 256) yinp[k] = embed[(size_t)id * 300 + k];
  } else {
    __shared__ float r2[4];
    int j = bx - 6433;
    float a = 0.f;
    for (int k = t; k < 32768; k += 256) a += pmat[(size_t)j * 32768 + k];
    a = wred_sum(a);
    if ((t & 63) == 0) r2[t >> 6] = a;
    __syncthreads();
    if (t == 0) nz[j] = r2[0] + r2[1] + r2[2] + r2[3];
  }
}

// ---------------- K2: scores GEMM, BM=128 BN=256 BK=64, XOR-swizzled LDS (slot ^= row&7)
__global__ __launch_bounds__(256, 2) void k_scores_gemm(
    const unsigned short* __restrict__ encb, const unsigned short* __restrict__ WaT,
    const float* __restrict__ hWa, const float* __restrict__ va,
    float* __restrict__ scoresP) {
  __shared__ __align__(16) unsigned short As[128 * 64];
  __shared__ __align__(16) unsigned short Bs[256 * 64];
  __shared__ float red[2][128];
  int mtile = blockIdx.x, ntile = blockIdx.y;
  int t = threadIdx.x, lane = t & 63, wid = t >> 6;
  int wr = wid >> 1, wc = wid & 1;
  int l15 = lane & 15, lg = lane >> 4;
  int r0 = mtile * 128;

  f32x4 acc[4][8];
#pragma unroll
  for (int m = 0; m < 4; m++)
#pragma unroll
    for (int n = 0; n < 8; n++) acc[m][n] = (f32x4){0.f, 0.f, 0.f, 0.f};

  for (int kt = 0; kt < 1024; kt += 64) {
#pragma unroll
    for (int p = 0; p < 4; p++) {
      int c = p * 256 + t;
      int row = c >> 3, slot = c & 7;
      const unsigned short* g =
          encb + (size_t)(r0 + row) * 1024 + kt + ((slot ^ (row & 7)) * 8);
      gl2lds16(g, &As[c * 8]);
    }
#pragma unroll
    for (int p = 0; p < 8; p++) {
      int c = p * 256 + t;
      int row = c >> 3, slot = c & 7;
      const unsigned short* g =
          WaT + (size_t)(ntile * 256 + row) * 1024 + kt + ((slot ^ (row & 7)) * 8);
      gl2lds16(g, &Bs[c * 8]);
    }
    __syncthreads();
#pragma unroll
    for (int ks = 0; ks < 2; ks++) {
      int q = ks * 4 + lg;
      short8 a[4];
#pragma unroll
      for (int m = 0; m < 4; m++) {
        int row = wr * 64 + m * 16 + l15;
        a[m] = *(const short8*)&As[row * 64 + ((q ^ (row & 7)) * 8)];
      }
#pragma unroll
      for (int n = 0; n < 8; n++) {
        int nr = wc * 128 + n * 16 + l15;
        short8 b = *(const short8*)&Bs[nr * 64 + ((q ^ (nr & 7)) * 8)];
#pragma unroll
        for (int m = 0; m < 4; m++)
          acc[m][n] = __builtin_amdgcn_mfma_f32_16x16x32_bf16(a[m], b, acc[m][n], 0, 0, 0);
      }
    }
    __syncthreads();
  }

  float vva[8], hba[8];
#pragma unroll
  for (int n = 0; n < 8; n++) {
    int col = ntile * 256 + wc * 128 + n * 16 + l15;
    vva[n] = va[col];
    hba[n] = hWa[col];
  }
#pragma unroll
  for (int m = 0; m < 4; m++) {
#pragma unroll
    for (int j = 0; j < 4; j++) {
      float p = 0.f;
#pragma unroll
      for (int n = 0; n < 8; n++) p += vva[n] * tanhf(acc[m][n][j] + hba[n]);
#pragma unroll
      for (int o = 1; o < 16; o <<= 1) p += __shfl_xor(p, o, 64);
      if (l15 == 0) red[wc][wr * 64 + m * 16 + lg * 4 + j] = p;
    }
  }
  __syncthreads();
  if (t < 128) scoresP[(size_t)ntile * 12288 + r0 + t] = red[0][t] + red[1][t];
}

// ---------------- K_MID: fused mid-section, 256 blocks, 7 device barriers
__global__ __launch_bounds__(256) void k_mid(
    const float* __restrict__ scoresP, float* __restrict__ scores,
    float* __restrict__ bmax, float* __restrict__ bz,
    const unsigned short* __restrict__ encb, float* __restrict__ partw,
    const float* __restrict__ Wg, float* __restrict__ wgP, const float* __restrict__ bg,
    const float* __restrict__ yinp, const float* __restrict__ hid,
    const float* __restrict__ Wchar, const float* __restrict__ bchar,
    const float* __restrict__ nz, float* __restrict__ weighted, int* __restrict__ sel,
    const float* __restrict__ pmat, const float* __restrict__ Wp, float* __restrict__ ppP,
    const float* __restrict__ bp, const float* __restrict__ hWh, const float* __restrict__ vv,
    float* __restrict__ attb, const float* __restrict__ Wy, float* __restrict__ yinP,
    const float* __restrict__ by, const float* __restrict__ Wih, const float* __restrict__ Whh,
    float* __restrict__ gatesP, float* __restrict__ dout, int* __restrict__ barr) {
  int bid = blockIdx.x, t = threadIdx.x;
  int* cnt = barr; int* gen = barr + 1;

  // ---- P1: scores reduce + per-block softmax stats (48 units)
  if (bid < 48) {
    __shared__ float r4[4];
    int r = bid * 256 + t;
    float s = 0.f;
#pragma unroll
    for (int nt = 0; nt < 4; nt++) s += scoresP[(size_t)nt * 12288 + r];
    scores[r] = s;
    float m = wred_max(s);
    if ((t & 63) == 0) r4[t >> 6] = m;
    __syncthreads();
    m = fmaxf(fmaxf(r4[0], r4[1]), fmaxf(r4[2], r4[3]));
    __syncthreads();
    float z = expf(s - m);
    z = wred_sum(z);
    if ((t & 63) == 0) r4[t >> 6] = z;
    __syncthreads();
    if (t == 0) { bmax[bid] = m; bz[bid] = r4[0] + r4[1] + r4[2] + r4[3]; }
  }
  gbar(cnt, gen, 256);

  // ---- P2: weighted_part (384 units; block does u=bid and u=bid+256)
  {
    __shared__ float wrow[64];
#pragma unroll
    for (int pass = 0; pass < 2; pass++) {
      int u = bid + pass * 256;
      if (u >= 384) break;
      int b = u >> 1, colq = u & 1;
      int seg = (b >= 128) ? 1 : 0;
      int sbase = seg ? 8192 : 0;
      int rb = seg ? (b - 128) * 64 : b * 64;
      if (t < 64) {
        int b0 = seg ? 32 : 0, cntn = seg ? 16 : 32;
        float mv = (t < cntn) ? bmax[b0 + t] : -1e30f;
        float m = wred_max(mv);
        float zv = (t < cntn) ? bz[b0 + t] * expf(bmax[b0 + t] - m) : 0.f;
        float z = wred_sum(zv);
        wrow[t] = expf(scores[sbase + rb + t] - m) / z;
      }
      __syncthreads();
      int c2 = colq * 512 + 2 * t;
      float a0 = 0.f, a1 = 0.f;
      size_t rowbase = (size_t)b * 64 * 1024;
#pragma unroll 8
      for (int r = 0; r < 64; r++) {
        unsigned uu = *(const unsigned*)&encb[rowbase + (size_t)r * 1024 + c2];
        float w = wrow[r];
        a0 += w * __uint_as_float(uu << 16);
        a1 += w * __uint_as_float(uu & 0xffff0000u);
      }
      float2 o; o.x = a0; o.y = a1;
      *(float2*)&partw[(size_t)b * 1024 + c2] = o;
      __syncthreads();
    }
  }
  gbar(cnt, gen, 256);

  // ---- P3: weighted_gemv (128 units: oq=u>>5, kq=u&31)
  if (bid < 128) {
    __shared__ float wxcL[64];
    int oq = bid >> 5, kq = bid & 31;
    if (t < 64) {
      float s = 0.f;
      if (kq < 16) {
        int d = kq * 64 + t;
#pragma unroll 8
        for (int b = 0; b < 128; b++) s += partw[(size_t)b * 1024 + d];
      } else {
        int d = (kq - 16) * 64 + t;
#pragma unroll 8
        for (int b = 128; b < 192; b++) s += partw[(size_t)b * 1024 + d];
      }
      wxcL[t] = s;
    }
    __syncthreads();
    int o = oq * 256 + t;
    int k0 = kq * 64;
    float acc = 0.f;
#pragma unroll 8
    for (int j = 0; j < 64; j++) acc += wxcL[j] * Wg[(size_t)(k0 + j) * 1024 + o];
    wgP[(size_t)kq * 1024 + o] = acc;
  }
  gbar(cnt, gen, 256);

  // ---- P4: wgfin + charsel (block 0)
  if (bid == 0) {
    __shared__ float WL[1024];
    __shared__ float red6[4][6];
    for (int q = 0; q < 4; q++) {
      int d = t + q * 256;
      float s = bg[d];
#pragma unroll 8
      for (int b = 0; b < 32; b++) s += wgP[(size_t)b * 1024 + d];
      WL[d] = s;
      weighted[d] = s;
      dout[OUT_W + d] = s;
    }
    __syncthreads();
    float p[6] = {0.f, 0.f, 0.f, 0.f, 0.f, 0.f};
    for (int k = t; k < 2348; k += 256) {
      float xv = (k < 300) ? yinp[k] : (k < 1324 ? hid[k - 300] : WL[k - 1324]);
#pragma unroll
      for (int ch = 0; ch < 6; ch++) p[ch] += xv * Wchar[k * 6 + ch];
    }
#pragma unroll
    for (int ch = 0; ch < 6; ch++) {
      float v = wred_sum(p[ch]);
      if ((t & 63) == 0) red6[t >> 6][ch] = v;
    }
    __syncthreads();
    if (t == 0) {
      float best = -1e30f; int si = 0;
      for (int ch = 0; ch < 6; ch++) {
        float lgt = red6[0][ch] + red6[1][ch] + red6[2][ch] + red6[3][ch] + bchar[ch];
        if (nz[ch] != 0.0f && lgt > best) { best = lgt; si = ch; }
      }
      *sel = si;
    }
  }
  gbar(cnt, gen, 256);

  // ---- P5: pp partials (64 units: oq=u>>4, kq=u&15)
  if (bid < 64) {
    __shared__ float sr[32][64];
    int oq = bid >> 4, kq = bid & 15;
    int row0 = (*sel) * 32;
    int k0 = kq * 64;
#pragma unroll
    for (int j = 0; j < 8; j++) {
      int idx2 = t + j * 256;
      int i = idx2 >> 6, kk = idx2 & 63;
      sr[i][kk] = pmat[(size_t)(row0 + i) * 1024 + k0 + kk];
    }
    __syncthreads();
    int o = oq * 256 + t;
    float acc[32];
#pragma unroll
    for (int i = 0; i < 32; i++) acc[i] = 0.f;
    for (int k = 0; k < 64; k++) {
      float w = Wp[(size_t)(k0 + k) * 1024 + o];
#pragma unroll
      for (int i = 0; i < 32; i++) acc[i] += sr[i][k] * w;
    }
#pragma unroll
    for (int i = 0; i < 32; i++) ppP[(size_t)kq * 32768 + i * 1024 + o] = acc[i];
  }
  gbar(cnt, gen, 256);

  // ---- P6: ppfin + att (33 units)
  if (bid < 33) {
    __shared__ float r4b[4];
    int i = bid;
    float pt = 0.f;
    if (i < 32) {
      for (int q = 0; q < 4; q++) {
        int d = t + q * 256;
        float s = bp[d];
#pragma unroll
        for (int kq = 0; kq < 16; kq++) s += ppP[(size_t)kq * 32768 + i * 1024 + d];
        pt += vv[d] * tanhf(hWh[d] + s);
      }
    } else {
      for (int q = 0; q < 4; q++) {
        int d = t + q * 256;
        pt += vv[d] * tanhf(hWh[d] + bp[d]);
      }
    }
    pt = wred_sum(pt);
    if ((t & 63) == 0) r4b[t >> 6] = pt;
    __syncthreads();
    if (t == 0) attb[i] = r4b[0] + r4b[1] + r4b[2] + r4b[3];
  }
  gbar(cnt, gen, 256);

  // ---- P7: pattn + yin partials (32 units)
  if (bid < 32) {
    __shared__ float sc32[32];
    __shared__ float XLb[74];
    if (t == 0) {
      float az = attb[32];
      float m = az;
#pragma unroll
      for (int i = 0; i < 32; i++) m = fmaxf(m, attb[i]);
      float Z = 160.0f * expf(az - m);
#pragma unroll
      for (int i = 0; i < 32; i++) Z += expf(attb[i] - m);
#pragma unroll
      for (int i = 0; i < 32; i++) sc32[i] = expf(attb[i] - m) / Z;
    }
    __syncthreads();
    if (bid == 0 && t < 32) dout[OUT_PS + t] = sc32[t];
    int base = bid * 74;
    int len = 2348 - base; if (len > 74) len = 74;
    int srow0 = (*sel) * 32;
    if (t < len) {
      int k = base + t;
      float xv;
      if (k < 300) xv = yinp[k];
      else if (k < 1324) xv = weighted[k - 300];
      else {
        int d = k - 1324;
        float acc = 0.f;
#pragma unroll
        for (int i = 0; i < 32; i++) acc += sc32[i] * pmat[(size_t)(srow0 + i) * 1024 + d];
        xv = acc;
      }
      XLb[t] = xv;
    }
    __syncthreads();
    for (int o = t; o < 300; o += 256) {
      float acc = 0.f;
      for (int j = 0; j < len; j++) acc += XLb[j] * Wy[(size_t)(base + j) * 300 + o];
      yinP[bid * 300 + o] = acc;
    }
  }
  gbar(cnt, gen, 256);

  // ---- P8: gates partials (512 units: bx=u>>3, kq=u&7; block does u=bid, u=bid+256)
  {
    __shared__ float YLb[40];
    __shared__ float red8[4][64];
#pragma unroll
    for (int pass = 0; pass < 2; pass++) {
      int u = bid + pass * 256;
      int bx = u >> 3, kq = u & 7;
      int k0i = kq * 38;
      int k1i = k0i + 38; if (k1i > 300) k1i = 300;
      if (t < k1i - k0i) {
        float s = by[k0i + t];
#pragma unroll 8
        for (int b = 0; b < 32; b++) s += yinP[b * 300 + k0i + t];
        YLb[t] = s;
      }
      __syncthreads();
      int ol = t & 63, kc = t >> 6;
      int o = bx * 64 + ol;
      float acc = 0.f;
      for (int k = k0i + kc; k < k1i; k += 4) acc += YLb[k - k0i] * Wih[(size_t)k * 4096 + o];
      int kh0 = kq * 128;
#pragma unroll 4
      for (int k = kh0 + kc; k < kh0 + 128; k += 4) acc += hid[k] * Whh[(size_t)k * 4096 + o];
      red8[kc][ol] = acc;
      __syncthreads();
      if (t < 64) {
        int oo = bx * 64 + t;
        gatesP[(size_t)kq * 4096 + oo] = red8[0][t] + red8[1][t] + red8[2][t] + red8[3][t];
      }
      __syncthreads();
    }
  }
}

// ---------------- K8 (LSTM folded in): h1 32-slice from gatesP, then float4 logits partials
__global__ __launch_bounds__(256) void k_out_gemv(const float* __restrict__ gatesP,
                                                  const float* __restrict__ bih,
                                                  const float* __restrict__ bhh,
                                                  const float* __restrict__ c0,
                                                  const float* __restrict__ Wout,
                                                  float* __restrict__ partK,
                                                  float* __restrict__ dout) {
  __shared__ float hh[32];
  int ks = blockIdx.x, cb = blockIdx.y, t = threadIdx.x;
  if (t < 32) {
    int d = ks * 32 + t;
    float gi = bih[d] + bhh[d];
    float gf = bih[1024 + d] + bhh[1024 + d];
    float gg = bih[2048 + d] + bhh[2048 + d];
    float go = bih[3072 + d] + bhh[3072 + d];
#pragma unroll
    for (int kq = 0; kq < 8; kq++) {
      const float* g = gatesP + (size_t)kq * 4096;
      gi += g[d]; gf += g[1024 + d]; gg += g[2048 + d]; go += g[3072 + d];
    }
    float c1 = sigmoidf(gf) * c0[d] + sigmoidf(gi) * tanhf(gg);
    float h1 = sigmoidf(go) * tanhf(c1);
    hh[t] = h1;
    if (cb == 0) { dout[OUT_H1 + d] = h1; dout[OUT_C1 + d] = c1; }
  }
  __syncthreads();
  const float* W = Wout + (size_t)ks * 32 * 50257;
  int c4 = cb * 1024 + t * 4;
  if (c4 + 4 <= 50257) {
    f32x4 a = (f32x4){0.f, 0.f, 0.f, 0.f};
#pragma unroll 4
    for (int k = 0; k < 32; k++) {
      f32x4u w = *(const f32x4u*)&W[(size_t)k * 50257 + c4];
      float h = hh[k];
      a[0] += h * w[0]; a[1] += h * w[1]; a[2] += h * w[2]; a[3] += h * w[3];
    }
    *(f32x4*)&partK[(size_t)ks * PKS + c4] = a;
  } else if (c4 < 50257) {
    for (int c = c4; c < 50257; c++) {
      float a = 0.f;
#pragma unroll 8
      for (int k = 0; k < 32; k++) a += hh[k] * W[(size_t)k * 50257 + c];
      partK[(size_t)ks * PKS + c] = a;
    }
  }
}

// ---------------- K9 fused: logits+stats, barrier, merge+softmax out (197 blocks)
__global__ __launch_bounds__(256) void k_logits_fin(const float* __restrict__ partK,
                                                    const float* __restrict__ bout,
                                                    float* __restrict__ logits,
                                                    float* __restrict__ bstat,
                                                    float* __restrict__ dout,
                                                    int* __restrict__ barr) {
  __shared__ float r4[4];
  __shared__ float r4z[4];
  int bx = blockIdx.x, t = threadIdx.x;
  int c = bx * 256 + t;
  float v = -1e30f;
  if (c < 50257) {
    v = bout[c];
#pragma unroll
    for (int ks = 0; ks < 32; ks++) v += partK[(size_t)ks * PKS + c];
    logits[c] = v;
  }
  float m = wred_max(v);
  if ((t & 63) == 0) r4[t >> 6] = m;
  __syncthreads();
  m = fmaxf(fmaxf(r4[0], r4[1]), fmaxf(r4[2], r4[3]));
  __syncthreads();
  float z = (c < 50257) ? expf(v - m) : 0.f;
  z = wred_sum(z);
  if ((t & 63) == 0) r4[t >> 6] = z;
  __syncthreads();
  if (t == 0) { bstat[bx] = m; bstat[256 + bx] = r4[0] + r4[1] + r4[2] + r4[3]; }

  gbar(barr + 2, barr + 3, 197);

  float mv = (t < 197) ? bstat[t] : -1e30f;
  float gm = wred_max(mv);
  if ((t & 63) == 0) r4[t >> 6] = gm;
  __syncthreads();
  gm = fmaxf(fmaxf(r4[0], r4[1]), fmaxf(r4[2], r4[3]));
  __syncthreads();
  float zv = (t < 197) ? bstat[256 + t] * expf(bstat[t] - gm) : 0.f;
  float gz = wred_sum(zv);
  if ((t & 63) == 0) r4z[t >> 6] = gz;
  __syncthreads();
  float Z = r4z[0] + r4z[1] + r4z[2] + r4z[3];
  if (c < 50257) dout[c] = expf(logits[c] - gm) / Z;
}

extern "C" void kernel_launch(void* const* d_in, const int* in_sizes, int n_in,
                              void* d_out, int out_size, void* d_ws, size_t ws_size,
                              hipStream_t stream) {
  (void)in_sizes; (void)n_in; (void)out_size; (void)ws_size;
  const int*   idx   = (const int*)  d_in[0];
  const float* ex    = (const float*)d_in[1];
  const float* ec    = (const float*)d_in[2];
  const float* pmat  = (const float*)d_in[3];
  const float* hid   = (const float*)d_in[4];
  const float* c0    = (const float*)d_in[5];
  const float* embed = (const float*)d_in[8];
  const float* Wa    = (const float*)d_in[9];
  const float* ba    = (const float*)d_in[10];
  const float* va    = (const float*)d_in[11];
  const float* Wg    = (const float*)d_in[12];
  const float* bg    = (const float*)d_in[13];
  const float* Wchar = (const float*)d_in[14];
  const float* bchar = (const float*)d_in[15];
  const float* Wp    = (const float*)d_in[16];
  const float* bp    = (const float*)d_in[17];
  const float* Wh    = (const float*)d_in[18];
  const float* bh    = (const float*)d_in[19];
  const float* vv    = (const float*)d_in[20];
  const float* Wy    = (const float*)d_in[21];
  const float* by    = (const float*)d_in[22];
  const float* Wih   = (const float*)d_in[23];
  const float* Whh   = (const float*)d_in[24];
  const float* bih   = (const float*)d_in[25];
  const float* bhh   = (const float*)d_in[26];
  const float* Wout  = (const float*)d_in[27];
  const float* bout  = (const float*)d_in[28];
  float* out = (float*)d_out;

  char* ws = (char*)d_ws;
  // Phase-1 zone (dead before k_out_gemv):
  unsigned short* encb = (unsigned short*)(ws + 0);         // 25,165,824
  unsigned short* WaT  = (unsigned short*)(ws + 25165824);  //  2,097,152 -> 27,262,976
  float* scoresP  = (float*)(ws + 27262976);                //    196,608 -> 27,459,584
  float* scores   = (float*)(ws + 27656192);                //     49,152 -> 27,705,344
  float* bmax     = (float*)(ws + 27705344);                //        256
  float* bz       = (float*)(ws + 27705600);                //        256
  float* partw    = (float*)(ws + 27705856);                //    786,432 -> 28,492,288
  float* wgP      = (float*)(ws + 28492288);                //    131,072 -> 28,623,360
  // Phase-2 zone (overlaps phase-1 only):
  float* partK    = (float*)(ws + 0);                       //  6,433,280 (32 x 50260 x 4)
  float* logits   = (float*)(ws + 6433280);                 //    201,152 -> 6,634,432
  // Persistent zone:
  float* ppP      = (float*)(ws + 28623360);                //  2,097,152 -> 30,720,512
  float* attb     = (float*)(ws + 30720512);                //        256
  float* yinP     = (float*)(ws + 30720768);                //     38,656 -> 30,759,424
  float* gatesP   = (float*)(ws + 30759424);                //    131,072 -> 30,890,496
  float* hWa      = (float*)(ws + 30890496);                //      4,096
  float* hWh      = (float*)(ws + 30894592);                //      4,096
  float* yinp     = (float*)(ws + 30898688);                //      1,536
  float* nz       = (float*)(ws + 30900224);                //        256
  float* weighted = (float*)(ws + 30900480);                //      4,096
  int*   sel      = (int*)  (ws + 30904576);                //        256
  float* bstat    = (float*)(ws + 30904832);                //      2,048
  int*   barr     = (int*)  (ws + 30906880);                //         16 -> 30,906,896 total

  k_prep<<<6439, 256, 0, stream>>>(ex, ec, Wa, ba, Wh, bh, hid, embed, idx, pmat,
                                   encb, WaT, hWa, hWh, yinp, nz, barr);
  k_scores_gemm<<<dim3(96, 4), 256, 0, stream>>>(encb, WaT, hWa, va, scoresP);
  k_mid<<<256, 256, 0, stream>>>(scoresP, scores, bmax, bz, encb, partw, Wg, wgP, bg,
                                 yinp, hid, Wchar, bchar, nz, weighted, sel, pmat, Wp,
                                 ppP, bp, hWh, vv, attb, Wy, yinP, by, Wih, Whh,
                                 gatesP, out, barr);
  k_out_gemv<<<dim3(32, 50), 256, 0, stream>>>(gatesP, bih, bhh, c0, Wout, partK, out);
  k_logits_fin<<<197, 256, 0, stream>>>(partK, bout, logits, bstat, out, barr);
}

// Round 9
// 247.532 us; speedup vs baseline: 2.2181x; 2.2181x over previous
//
#include <hip/hip_runtime.h>
#include <hip/hip_bf16.h>
#include <math.h>

typedef short short8 __attribute__((ext_vector_type(8)));
typedef float f32x4 __attribute__((ext_vector_type(4)));
typedef float f32x4u __attribute__((ext_vector_type(4), aligned(4)));

#define DEV static __device__ __forceinline__

DEV void gl2lds16(const void* g, void* l) {
  __builtin_amdgcn_global_load_lds(
      (const __attribute__((address_space(1))) unsigned int*)g,
      (__attribute__((address_space(3))) unsigned int*)l, 16, 0, 0);
}

DEV float wred_sum(float v) {
#pragma unroll
  for (int o = 1; o < 64; o <<= 1) v += __shfl_xor(v, o, 64);
  return v;
}
DEV float wred_max(float v) {
#pragma unroll
  for (int o = 1; o < 64; o <<= 1) v = fmaxf(v, __shfl_xor(v, o, 64));
  return v;
}
DEV float sigmoidf(float x) { return 1.0f / (1.0f + expf(-x)); }

DEV unsigned short f2bf(float x) {
  unsigned u = __float_as_uint(x);
  unsigned rr = (u + 0x7fffu + ((u >> 16) & 1u)) >> 16;
  return (unsigned short)rr;
}

DEV short8 cvt8(float4 f0, float4 f1) {
  union { short8 s; unsigned u[4]; } r;
  asm("v_cvt_pk_bf16_f32 %0, %1, %2" : "=v"(r.u[0]) : "v"(f0.x), "v"(f0.y));
  asm("v_cvt_pk_bf16_f32 %0, %1, %2" : "=v"(r.u[1]) : "v"(f0.z), "v"(f0.w));
  asm("v_cvt_pk_bf16_f32 %0, %1, %2" : "=v"(r.u[2]) : "v"(f1.x), "v"(f1.y));
  asm("v_cvt_pk_bf16_f32 %0, %1, %2" : "=v"(r.u[3]) : "v"(f1.z), "v"(f1.w));
  return r.s;
}

// output layout (floats): out[50257] | h1[1024] | c1[1024] | weighted[1024] | psel[32]
#define OUT_H1 50257
#define OUT_C1 51281
#define OUT_W  52305
#define OUT_PS 53329
#define PKS 50260

// ---------------- K0 "k_prep": enc->bf16 | Wa_bot transpose->bf16 | h-matvecs | embed | nz
__global__ void k_prep(const float* __restrict__ ex, const float* __restrict__ ec,
                       const float* __restrict__ Wa, const float* __restrict__ ba,
                       const float* __restrict__ Wh, const float* __restrict__ bh,
                       const float* __restrict__ hid, const float* __restrict__ embed,
                       const int* __restrict__ idx, const float* __restrict__ pmat,
                       unsigned short* __restrict__ encb, unsigned short* __restrict__ WaT,
                       float* __restrict__ hWa, float* __restrict__ hWh,
                       float* __restrict__ yinp, float* __restrict__ nz) {
  int bx = blockIdx.x, t = threadIdx.x;
  if (bx < 6144) {
    size_t i = ((size_t)bx * 256 + t) * 8;
    const float* src = (i < 8388608) ? (ex + i) : (ec + (i - 8388608));
    float4 f0 = *(const float4*)src;
    float4 f1 = *(const float4*)(src + 4);
    *(short8*)&encb[i] = cvt8(f0, f1);
  } else if (bx < 6400) {
    __shared__ float tile[64][65];
    int bb = bx - 6144;
    int bi = bb >> 4, bj = bb & 15;
    int c = t & 63, rq = t >> 6;
#pragma unroll
    for (int rr = 0; rr < 16; rr++) {
      int kl = rr * 4 + rq;
      tile[kl][c] = Wa[(size_t)(1024 + bi * 64 + kl) * 1024 + bj * 64 + c];
    }
    __syncthreads();
#pragma unroll
    for (int rr = 0; rr < 16; rr++) {
      int nl = rr * 4 + rq;
      WaT[(size_t)(bj * 64 + nl) * 1024 + bi * 64 + c] = f2bf(tile[c][nl]);
    }
  } else if (bx < 6432) {
    __shared__ float red[4][64];
    int bb = bx - 6400;
    int ol = t & 63, kc = t >> 6;
    int o = bb * 64 + ol;
    const float* W = (o < 1024) ? Wa : Wh;
    int col = (o < 1024) ? o : (o - 1024);
    float acc = 0.f;
#pragma unroll 4
    for (int k = kc * 256; k < kc * 256 + 256; k++) acc += hid[k] * W[(size_t)k * 1024 + col];
    red[kc][ol] = acc;
    __syncthreads();
    if (t < 64) {
      int oo = bb * 64 + t;
      float s = red[0][t] + red[1][t] + red[2][t] + red[3][t];
      if (oo < 1024) hWa[oo] = s + ba[oo];
      else hWh[oo - 1024] = s + bh[oo - 1024];
    }
  } else if (bx == 6432) {
    int id = idx[0];
    for (int k = t; k < 300; k += 256) yinp[k] = embed[(size_t)id * 300 + k];
  } else {
    __shared__ float r2[4];
    int j = bx - 6433;
    float a = 0.f;
    for (int k = t; k < 32768; k += 256) a += pmat[(size_t)j * 32768 + k];
    a = wred_sum(a);
    if ((t & 63) == 0) r2[t >> 6] = a;
    __syncthreads();
    if (t == 0) nz[j] = r2[0] + r2[1] + r2[2] + r2[3];
  }
}

// ---------------- K2: scores GEMM, BM=128 BN=256 BK=64, XOR-swizzled LDS (slot ^= row&7)
__global__ __launch_bounds__(256, 2) void k_scores_gemm(
    const unsigned short* __restrict__ encb, const unsigned short* __restrict__ WaT,
    const float* __restrict__ hWa, const float* __restrict__ va,
    float* __restrict__ scoresP) {
  __shared__ __align__(16) unsigned short As[128 * 64];
  __shared__ __align__(16) unsigned short Bs[256 * 64];
  __shared__ float red[2][128];
  int mtile = blockIdx.x, ntile = blockIdx.y;
  int t = threadIdx.x, lane = t & 63, wid = t >> 6;
  int wr = wid >> 1, wc = wid & 1;
  int l15 = lane & 15, lg = lane >> 4;
  int r0 = mtile * 128;

  f32x4 acc[4][8];
#pragma unroll
  for (int m = 0; m < 4; m++)
#pragma unroll
    for (int n = 0; n < 8; n++) acc[m][n] = (f32x4){0.f, 0.f, 0.f, 0.f};

  for (int kt = 0; kt < 1024; kt += 64) {
#pragma unroll
    for (int p = 0; p < 4; p++) {
      int c = p * 256 + t;
      int row = c >> 3, slot = c & 7;
      const unsigned short* g =
          encb + (size_t)(r0 + row) * 1024 + kt + ((slot ^ (row & 7)) * 8);
      gl2lds16(g, &As[c * 8]);
    }
#pragma unroll
    for (int p = 0; p < 8; p++) {
      int c = p * 256 + t;
      int row = c >> 3, slot = c & 7;
      const unsigned short* g =
          WaT + (size_t)(ntile * 256 + row) * 1024 + kt + ((slot ^ (row & 7)) * 8);
      gl2lds16(g, &Bs[c * 8]);
    }
    __syncthreads();
#pragma unroll
    for (int ks = 0; ks < 2; ks++) {
      int q = ks * 4 + lg;
      short8 a[4];
#pragma unroll
      for (int m = 0; m < 4; m++) {
        int row = wr * 64 + m * 16 + l15;
        a[m] = *(const short8*)&As[row * 64 + ((q ^ (row & 7)) * 8)];
      }
#pragma unroll
      for (int n = 0; n < 8; n++) {
        int nr = wc * 128 + n * 16 + l15;
        short8 b = *(const short8*)&Bs[nr * 64 + ((q ^ (nr & 7)) * 8)];
#pragma unroll
        for (int m = 0; m < 4; m++)
          acc[m][n] = __builtin_amdgcn_mfma_f32_16x16x32_bf16(a[m], b, acc[m][n], 0, 0, 0);
      }
    }
    __syncthreads();
  }

  float vva[8], hba[8];
#pragma unroll
  for (int n = 0; n < 8; n++) {
    int col = ntile * 256 + wc * 128 + n * 16 + l15;
    vva[n] = va[col];
    hba[n] = hWa[col];
  }
#pragma unroll
  for (int m = 0; m < 4; m++) {
#pragma unroll
    for (int j = 0; j < 4; j++) {
      float p = 0.f;
#pragma unroll
      for (int n = 0; n < 8; n++) p += vva[n] * tanhf(acc[m][n][j] + hba[n]);
#pragma unroll
      for (int o = 1; o < 16; o <<= 1) p += __shfl_xor(p, o, 64);
      if (l15 == 0) red[wc][wr * 64 + m * 16 + lg * 4 + j] = p;
    }
  }
  __syncthreads();
  if (t < 128) scoresP[(size_t)ntile * 12288 + r0 + t] = red[0][t] + red[1][t];
}

// ---------------- K2b: scores[r] = sum over 4 ntiles ; fused per-block softmax stats
__global__ void k_scores_reduce(const float* __restrict__ scoresP, float* __restrict__ scores,
                                float* __restrict__ bmax, float* __restrict__ bz) {
  __shared__ float r4[4];
  int bx = blockIdx.x, t = threadIdx.x;
  int r = bx * 256 + t;
  float s = 0.f;
#pragma unroll
  for (int nt = 0; nt < 4; nt++) s += scoresP[(size_t)nt * 12288 + r];
  scores[r] = s;
  float m = wred_max(s);
  if ((t & 63) == 0) r4[t >> 6] = m;
  __syncthreads();
  m = fmaxf(fmaxf(r4[0], r4[1]), fmaxf(r4[2], r4[3]));
  __syncthreads();
  float z = expf(s - m);
  z = wred_sum(z);
  if ((t & 63) == 0) r4[t >> 6] = z;
  __syncthreads();
  if (t == 0) { bmax[bx] = m; bz[bx] = r4[0] + r4[1] + r4[2] + r4[3]; }
}

// ---------------- K3: weighted-sum partials from bf16 encb; 64-row x 512-col tiles
__global__ void k_weighted_part(const unsigned short* __restrict__ encb,
                                const float* __restrict__ scores, const float* __restrict__ bmax,
                                const float* __restrict__ bz, float* __restrict__ partw) {
  __shared__ float wrow[64];
  int b = blockIdx.x, colq = blockIdx.y, t = threadIdx.x;
  int seg = (b >= 128) ? 1 : 0;
  int sbase = seg ? 8192 : 0;
  int rb = seg ? (b - 128) * 64 : b * 64;
  if (t < 64) {
    int b0 = seg ? 32 : 0, cnt = seg ? 16 : 32;
    float mv = (t < cnt) ? bmax[b0 + t] : -1e30f;
    float m = wred_max(mv);
    float zv = (t < cnt) ? bz[b0 + t] * expf(bmax[b0 + t] - m) : 0.f;
    float z = wred_sum(zv);
    wrow[t] = expf(scores[sbase + rb + t] - m) / z;
  }
  __syncthreads();
  int c2 = colq * 512 + 2 * t;
  float a0 = 0.f, a1 = 0.f;
  size_t rowbase = (size_t)b * 64 * 1024;
#pragma unroll 8
  for (int r = 0; r < 64; r++) {
    unsigned u = *(const unsigned*)&encb[rowbase + (size_t)r * 1024 + c2];
    float w = wrow[r];
    a0 += w * __uint_as_float(u << 16);
    a1 += w * __uint_as_float(u & 0xffff0000u);
  }
  float2 o; o.x = a0; o.y = a1;
  *(float2*)&partw[(size_t)b * 1024 + c2] = o;
}

// ---------------- K4 (combine folded in): wgP[kq][o] = wxc[kq-slice] @ Wg-slice
__global__ void k_weighted_gemv(const float* __restrict__ partw, const float* __restrict__ Wg,
                                float* __restrict__ wgP) {
  __shared__ float wxcL[64];
  int oq = blockIdx.x, kq = blockIdx.y, t = threadIdx.x;
  if (t < 64) {
    float s = 0.f;
    if (kq < 16) {
      int d = kq * 64 + t;
#pragma unroll 8
      for (int b = 0; b < 128; b++) s += partw[(size_t)b * 1024 + d];
    } else {
      int d = (kq - 16) * 64 + t;
#pragma unroll 8
      for (int b = 128; b < 192; b++) s += partw[(size_t)b * 1024 + d];
    }
    wxcL[t] = s;
  }
  __syncthreads();
  int o = oq * 256 + t;
  int k0 = kq * 64;
  float acc = 0.f;
#pragma unroll 8
  for (int j = 0; j < 64; j++) acc += wxcL[j] * Wg[(size_t)(k0 + j) * 1024 + o];
  wgP[(size_t)kq * 1024 + o] = acc;
}

// ---------------- K5 merged: block0 = wgfin+charsel+writes ; blocks 1..64 = pp partials
// (pp blocks recompute sel redundantly from wgP — no cross-block dependency)
__global__ void k_wgfin_pp(const float* __restrict__ wgP, const float* __restrict__ bg,
                           const float* __restrict__ yinp, const float* __restrict__ hid,
                           const float* __restrict__ Wchar, const float* __restrict__ bchar,
                           const float* __restrict__ nz, float* __restrict__ weighted,
                           int* __restrict__ sel, const float* __restrict__ pmat,
                           const float* __restrict__ Wp, float* __restrict__ ppP,
                           float* __restrict__ dout) {
  __shared__ float WL[1024];
  __shared__ float red6[4][6];
  __shared__ int ssel;
  int bid = blockIdx.x, t = threadIdx.x;
  // all blocks: weighted = sum(wgP) + bg
  for (int q = 0; q < 4; q++) {
    int d = t + q * 256;
    float s = bg[d];
#pragma unroll 8
    for (int b = 0; b < 32; b++) s += wgP[(size_t)b * 1024 + d];
    WL[d] = s;
    if (bid == 0) { weighted[d] = s; dout[OUT_W + d] = s; }
  }
  __syncthreads();
  // all blocks: char gate logits -> local sel
  float p[6] = {0.f, 0.f, 0.f, 0.f, 0.f, 0.f};
  for (int k = t; k < 2348; k += 256) {
    float xv = (k < 300) ? yinp[k] : (k < 1324 ? hid[k - 300] : WL[k - 1324]);
#pragma unroll
    for (int ch = 0; ch < 6; ch++) p[ch] += xv * Wchar[k * 6 + ch];
  }
#pragma unroll
  for (int ch = 0; ch < 6; ch++) {
    float v = wred_sum(p[ch]);
    if ((t & 63) == 0) red6[t >> 6][ch] = v;
  }
  __syncthreads();
  if (t == 0) {
    float best = -1e30f; int si = 0;
    for (int ch = 0; ch < 6; ch++) {
      float lgt = red6[0][ch] + red6[1][ch] + red6[2][ch] + red6[3][ch] + bchar[ch];
      if (nz[ch] != 0.0f && lgt > best) { best = lgt; si = ch; }
    }
    ssel = si;
    if (bid == 0) *sel = si;
  }
  __syncthreads();
  if (bid == 0) return;
  // blocks 1..64: pp partials, unit u = bid-1: oq=u>>4, kq=u&15
  __shared__ float sr[32][64];
  int u = bid - 1;
  int oq = u >> 4, kq = u & 15;
  int row0 = ssel * 32;
  int k0 = kq * 64;
#pragma unroll
  for (int j = 0; j < 8; j++) {
    int idx2 = t + j * 256;
    int i = idx2 >> 6, kk = idx2 & 63;
    sr[i][kk] = pmat[(size_t)(row0 + i) * 1024 + k0 + kk];
  }
  __syncthreads();
  int o = oq * 256 + t;
  float acc[32];
#pragma unroll
  for (int i = 0; i < 32; i++) acc[i] = 0.f;
  for (int k = 0; k < 64; k++) {
    float w = Wp[(size_t)(k0 + k) * 1024 + o];
#pragma unroll
    for (int i = 0; i < 32; i++) acc[i] += sr[i][k] * w;
  }
#pragma unroll
  for (int i = 0; i < 32; i++) ppP[(size_t)kq * 32768 + i * 1024 + o] = acc[i];
}

// ---------------- K6b: pp[i] = sum ppP + bp ; att[i] = vv . tanh(hWh+pp)
__global__ void k_ppfin_att(const float* __restrict__ ppP, const float* __restrict__ bp,
                            const float* __restrict__ hWh, const float* __restrict__ vv,
                            float* __restrict__ attb) {
  __shared__ float r4[4];
  int i = blockIdx.x, t = threadIdx.x;
  float pt = 0.f;
  if (i < 32) {
    for (int q = 0; q < 4; q++) {
      int d = t + q * 256;
      float s = bp[d];
#pragma unroll
      for (int kq = 0; kq < 16; kq++) s += ppP[(size_t)kq * 32768 + i * 1024 + d];
      pt += vv[d] * tanhf(hWh[d] + s);
    }
  } else {
    for (int q = 0; q < 4; q++) {
      int d = t + q * 256;
      pt += vv[d] * tanhf(hWh[d] + bp[d]);
    }
  }
  pt = wred_sum(pt);
  if ((t & 63) == 0) r4[t >> 6] = pt;
  __syncthreads();
  if (t == 0) attb[i] = r4[0] + r4[1] + r4[2] + r4[3];
}

// ---------------- K7a (pattn folded): softmax(att) ; p_attn on demand ; y_in partials
__global__ void k_pattn_yin(const float* __restrict__ attb, const float* __restrict__ pmat,
                            const int* __restrict__ sel, const float* __restrict__ yinp,
                            const float* __restrict__ weighted, const float* __restrict__ Wy,
                            float* __restrict__ yinP, float* __restrict__ dout) {
  __shared__ float sc32[32];
  __shared__ float XLb[74];
  int b = blockIdx.x, t = threadIdx.x;
  if (t == 0) {
    float az = attb[32];
    float m = az;
#pragma unroll
    for (int i = 0; i < 32; i++) m = fmaxf(m, attb[i]);
    float Z = 160.0f * expf(az - m);
#pragma unroll
    for (int i = 0; i < 32; i++) Z += expf(attb[i] - m);
#pragma unroll
    for (int i = 0; i < 32; i++) sc32[i] = expf(attb[i] - m) / Z;
  }
  __syncthreads();
  if (b == 0 && t < 32) dout[OUT_PS + t] = sc32[t];
  int base = b * 74;
  int len = 2348 - base; if (len > 74) len = 74;
  int srow0 = (*sel) * 32;
  if (t < len) {
    int k = base + t;
    float xv;
    if (k < 300) xv = yinp[k];
    else if (k < 1324) xv = weighted[k - 300];
    else {
      int d = k - 1324;
      float acc = 0.f;
#pragma unroll
      for (int i = 0; i < 32; i++) acc += sc32[i] * pmat[(size_t)(srow0 + i) * 1024 + d];
      xv = acc;
    }
    XLb[t] = xv;
  }
  __syncthreads();
  if (t < 300) {
    float acc = 0.f;
    for (int j = 0; j < len; j++) acc += XLb[j] * Wy[(size_t)(base + j) * 300 + t];
    yinP[b * 300 + t] = acc;
  }
}

// ---------------- K7b: gatesP[kq] = y_in@Wih + h0@Whh partials (k-split 8)
__global__ void k_gates_part(const float* __restrict__ yinP, const float* __restrict__ by,
                             const float* __restrict__ hid,
                             const float* __restrict__ Wih, const float* __restrict__ Whh,
                             float* __restrict__ gatesP) {
  __shared__ float YLb[40];
  __shared__ float red[4][64];
  int bx = blockIdx.x, kq = blockIdx.y, t = threadIdx.x;
  int k0i = kq * 38;
  int k1i = k0i + 38; if (k1i > 300) k1i = 300;
  if (t < k1i - k0i) {
    float s = by[k0i + t];
#pragma unroll 8
    for (int b = 0; b < 32; b++) s += yinP[b * 300 + k0i + t];
    YLb[t] = s;
  }
  __syncthreads();
  int ol = t & 63, kc = t >> 6;
  int o = bx * 64 + ol;
  float acc = 0.f;
  for (int k = k0i + kc; k < k1i; k += 4) acc += YLb[k - k0i] * Wih[(size_t)k * 4096 + o];
  int kh0 = kq * 128;
#pragma unroll 4
  for (int k = kh0 + kc; k < kh0 + 128; k += 4) acc += hid[k] * Whh[(size_t)k * 4096 + o];
  red[kc][ol] = acc;
  __syncthreads();
  if (t < 64) {
    int oo = bx * 64 + t;
    gatesP[(size_t)kq * 4096 + oo] = red[0][t] + red[1][t] + red[2][t] + red[3][t];
  }
}

// ---------------- K8 (LSTM folded in): h1 32-slice from gatesP, then float4 logits partials
__global__ __launch_bounds__(256) void k_out_gemv(const float* __restrict__ gatesP,
                                                  const float* __restrict__ bih,
                                                  const float* __restrict__ bhh,
                                                  const float* __restrict__ c0,
                                                  const float* __restrict__ Wout,
                                                  float* __restrict__ partK,
                                                  float* __restrict__ dout) {
  __shared__ float hh[32];
  int ks = blockIdx.x, cb = blockIdx.y, t = threadIdx.x;
  if (t < 32) {
    int d = ks * 32 + t;
    float gi = bih[d] + bhh[d];
    float gf = bih[1024 + d] + bhh[1024 + d];
    float gg = bih[2048 + d] + bhh[2048 + d];
    float go = bih[3072 + d] + bhh[3072 + d];
#pragma unroll
    for (int kq = 0; kq < 8; kq++) {
      const float* g = gatesP + (size_t)kq * 4096;
      gi += g[d]; gf += g[1024 + d]; gg += g[2048 + d]; go += g[3072 + d];
    }
    float c1 = sigmoidf(gf) * c0[d] + sigmoidf(gi) * tanhf(gg);
    float h1 = sigmoidf(go) * tanhf(c1);
    hh[t] = h1;
    if (cb == 0) { dout[OUT_H1 + d] = h1; dout[OUT_C1 + d] = c1; }
  }
  __syncthreads();
  const float* W = Wout + (size_t)ks * 32 * 50257;
  int c4 = cb * 1024 + t * 4;
  if (c4 + 4 <= 50257) {
    f32x4 a = (f32x4){0.f, 0.f, 0.f, 0.f};
#pragma unroll 4
    for (int k = 0; k < 32; k++) {
      f32x4u w = *(const f32x4u*)&W[(size_t)k * 50257 + c4];
      float h = hh[k];
      a[0] += h * w[0]; a[1] += h * w[1]; a[2] += h * w[2]; a[3] += h * w[3];
    }
    *(f32x4*)&partK[(size_t)ks * PKS + c4] = a;
  } else if (c4 < 50257) {
    for (int c = c4; c < 50257; c++) {
      float a = 0.f;
#pragma unroll 8
      for (int k = 0; k < 32; k++) a += hh[k] * W[(size_t)k * 50257 + c];
      partK[(size_t)ks * PKS + c] = a;
    }
  }
}

// ---------------- K9a: logits = sum partials + bout ; per-block max & sumexp (197 blocks)
__global__ void k_logits_stats(const float* __restrict__ partK, const float* __restrict__ bout,
                               float* __restrict__ logits, float* __restrict__ bstat) {
  __shared__ float r4[4];
  int bx = blockIdx.x, t = threadIdx.x;
  int c = bx * 256 + t;
  float v = -1e30f;
  if (c < 50257) {
    v = bout[c];
#pragma unroll
    for (int ks = 0; ks < 32; ks++) v += partK[(size_t)ks * PKS + c];
    logits[c] = v;
  }
  float m = wred_max(v);
  if ((t & 63) == 0) r4[t >> 6] = m;
  __syncthreads();
  m = fmaxf(fmaxf(r4[0], r4[1]), fmaxf(r4[2], r4[3]));
  __syncthreads();
  float z = (c < 50257) ? expf(v - m) : 0.f;
  z = wred_sum(z);
  if ((t & 63) == 0) r4[t >> 6] = z;
  __syncthreads();
  if (t == 0) { bstat[bx] = m; bstat[256 + bx] = r4[0] + r4[1] + r4[2] + r4[3]; }
}

// ---------------- K9c: merge stats (redundant per block) + out = exp(logit - M)/Z
__global__ void k_out_final(const float* __restrict__ bstat, const float* __restrict__ logits,
                            float* __restrict__ dout) {
  __shared__ float r4m[4], r4z[4];
  int bx = blockIdx.x, t = threadIdx.x;
  float mv = (t < 197) ? bstat[t] : -1e30f;
  float m = wred_max(mv);
  if ((t & 63) == 0) r4m[t >> 6] = m;
  __syncthreads();
  m = fmaxf(fmaxf(r4m[0], r4m[1]), fmaxf(r4m[2], r4m[3]));
  __syncthreads();
  float zv = (t < 197) ? bstat[256 + t] * expf(bstat[t] - m) : 0.f;
  float z = wred_sum(zv);
  if ((t & 63) == 0) r4z[t >> 6] = z;
  __syncthreads();
  float Z = r4z[0] + r4z[1] + r4z[2] + r4z[3];
  int c = bx * 256 + t;
  if (c < 50257) dout[c] = expf(logits[c] - m) / Z;
}

extern "C" void kernel_launch(void* const* d_in, const int* in_sizes, int n_in,
                              void* d_out, int out_size, void* d_ws, size_t ws_size,
                              hipStream_t stream) {
  (void)in_sizes; (void)n_in; (void)out_size; (void)ws_size;
  const int*   idx   = (const int*)  d_in[0];
  const float* ex    = (const float*)d_in[1];
  const float* ec    = (const float*)d_in[2];
  const float* pmat  = (const float*)d_in[3];
  const float* hid   = (const float*)d_in[4];
  const float* c0    = (const float*)d_in[5];
  const float* embed = (const float*)d_in[8];
  const float* Wa    = (const float*)d_in[9];
  const float* ba    = (const float*)d_in[10];
  const float* va    = (const float*)d_in[11];
  const float* Wg    = (const float*)d_in[12];
  const float* bg    = (const float*)d_in[13];
  const float* Wchar = (const float*)d_in[14];
  const float* bchar = (const float*)d_in[15];
  const float* Wp    = (const float*)d_in[16];
  const float* bp    = (const float*)d_in[17];
  const float* Wh    = (const float*)d_in[18];
  const float* bh    = (const float*)d_in[19];
  const float* vv    = (const float*)d_in[20];
  const float* Wy    = (const float*)d_in[21];
  const float* by    = (const float*)d_in[22];
  const float* Wih   = (const float*)d_in[23];
  const float* Whh   = (const float*)d_in[24];
  const float* bih   = (const float*)d_in[25];
  const float* bhh   = (const float*)d_in[26];
  const float* Wout  = (const float*)d_in[27];
  const float* bout  = (const float*)d_in[28];
  float* out = (float*)d_out;

  char* ws = (char*)d_ws;
  // Phase-1 zone (dead before k_out_gemv):
  unsigned short* encb = (unsigned short*)(ws + 0);         // 25,165,824
  unsigned short* WaT  = (unsigned short*)(ws + 25165824);  //  2,097,152 -> 27,262,976
  float* scoresP  = (float*)(ws + 27262976);                //    196,608 -> 27,459,584
  float* scores   = (float*)(ws + 27656192);                //     49,152 -> 27,705,344
  float* bmax     = (float*)(ws + 27705344);                //        256
  float* bz       = (float*)(ws + 27705600);                //        256
  float* partw    = (float*)(ws + 27705856);                //    786,432 -> 28,492,288
  float* wgP      = (float*)(ws + 28492288);                //    131,072 -> 28,623,360
  // Phase-2 zone (overlaps phase-1 only):
  float* partK    = (float*)(ws + 0);                       //  6,433,280 (32 x 50260 x 4)
  float* logits   = (float*)(ws + 6433280);                 //    201,152 -> 6,634,432
  // Persistent zone:
  float* ppP      = (float*)(ws + 28623360);                //  2,097,152 -> 30,720,512
  float* attb     = (float*)(ws + 30720512);                //        256
  float* yinP     = (float*)(ws + 30720768);                //     38,656 -> 30,759,424
  float* gatesP   = (float*)(ws + 30759424);                //    131,072 -> 30,890,496
  float* hWa      = (float*)(ws + 30890496);                //      4,096
  float* hWh      = (float*)(ws + 30894592);                //      4,096
  float* yinp     = (float*)(ws + 30898688);                //      1,536
  float* nz       = (float*)(ws + 30900224);                //        256
  float* weighted = (float*)(ws + 30900480);                //      4,096
  int*   sel      = (int*)  (ws + 30904576);                //        256
  float* bstat    = (float*)(ws + 30904832);                //      2,048 -> 30,906,880 total

  k_prep<<<6439, 256, 0, stream>>>(ex, ec, Wa, ba, Wh, bh, hid, embed, idx, pmat,
                                   encb, WaT, hWa, hWh, yinp, nz);
  k_scores_gemm<<<dim3(96, 4), 256, 0, stream>>>(encb, WaT, hWa, va, scoresP);
  k_scores_reduce<<<48, 256, 0, stream>>>(scoresP, scores, bmax, bz);
  k_weighted_part<<<dim3(192, 2), 256, 0, stream>>>(encb, scores, bmax, bz, partw);
  k_weighted_gemv<<<dim3(4, 32), 256, 0, stream>>>(partw, Wg, wgP);
  k_wgfin_pp<<<65, 256, 0, stream>>>(wgP, bg, yinp, hid, Wchar, bchar, nz, weighted, sel,
                                     pmat, Wp, ppP, out);
  k_ppfin_att<<<33, 256, 0, stream>>>(ppP, bp, hWh, vv, attb);
  k_pattn_yin<<<32, 320, 0, stream>>>(attb, pmat, sel, yinp, weighted, Wy, yinP, out);
  k_gates_part<<<dim3(64, 8), 256, 0, stream>>>(yinP, by, hid, Wih, Whh, gatesP);
  k_out_gemv<<<dim3(32, 50), 256, 0, stream>>>(gatesP, bih, bhh, c0, Wout, partK, out);
  k_logits_stats<<<197, 256, 0, stream>>>(partK, bout, logits, bstat);
  k_out_final<<<197, 256, 0, stream>>>(bstat, logits, out);
}

// Round 10
// 246.456 us; speedup vs baseline: 2.2277x; 1.0044x over previous
//
#include <hip/hip_runtime.h>
#include <hip/hip_bf16.h>
#include <math.h>

typedef short short8 __attribute__((ext_vector_type(8)));
typedef float f32x4 __attribute__((ext_vector_type(4)));
typedef float f32x4u __attribute__((ext_vector_type(4), aligned(4)));

#define DEV static __device__ __forceinline__

DEV void gl2lds16(const void* g, void* l) {
  __builtin_amdgcn_global_load_lds(
      (const __attribute__((address_space(1))) unsigned int*)g,
      (__attribute__((address_space(3))) unsigned int*)l, 16, 0, 0);
}

DEV float wred_sum(float v) {
#pragma unroll
  for (int o = 1; o < 64; o <<= 1) v += __shfl_xor(v, o, 64);
  return v;
}
DEV float wred_max(float v) {
#pragma unroll
  for (int o = 1; o < 64; o <<= 1) v = fmaxf(v, __shfl_xor(v, o, 64));
  return v;
}
DEV float sigmoidf(float x) { return 1.0f / (1.0f + expf(-x)); }

DEV unsigned short f2bf(float x) {
  unsigned u = __float_as_uint(x);
  unsigned rr = (u + 0x7fffu + ((u >> 16) & 1u)) >> 16;
  return (unsigned short)rr;
}

DEV short8 cvt8(float4 f0, float4 f1) {
  union { short8 s; unsigned u[4]; } r;
  asm("v_cvt_pk_bf16_f32 %0, %1, %2" : "=v"(r.u[0]) : "v"(f0.x), "v"(f0.y));
  asm("v_cvt_pk_bf16_f32 %0, %1, %2" : "=v"(r.u[1]) : "v"(f0.z), "v"(f0.w));
  asm("v_cvt_pk_bf16_f32 %0, %1, %2" : "=v"(r.u[2]) : "v"(f1.x), "v"(f1.y));
  asm("v_cvt_pk_bf16_f32 %0, %1, %2" : "=v"(r.u[3]) : "v"(f1.z), "v"(f1.w));
  return r.s;
}

// output layout (floats): out[50257] | h1[1024] | c1[1024] | weighted[1024] | psel[32]
#define OUT_H1 50257
#define OUT_C1 51281
#define OUT_W  52305
#define OUT_PS 53329
#define PKS 50260

// ---------------- K0 "k_prep": enc->bf16 | WaT | hWa/hWh | hWhh(+biases) | embed+yin+zero | nz
// grid: [0,6144) enc ; [6144,6400) bT ; [6400,6432) hWa/hWh ; [6432,6496) hWhh ;
//       6496 embed/yin/zero-scores ; [6497,6503) nz
__global__ void k_prep(const float* __restrict__ ex, const float* __restrict__ ec,
                       const float* __restrict__ Wa, const float* __restrict__ ba,
                       const float* __restrict__ Wh, const float* __restrict__ bh,
                       const float* __restrict__ Whh, const float* __restrict__ bih,
                       const float* __restrict__ bhh,
                       const float* __restrict__ hid, const float* __restrict__ embed,
                       const int* __restrict__ idx, const float* __restrict__ pmat,
                       const float* __restrict__ by,
                       unsigned short* __restrict__ encb, unsigned short* __restrict__ WaT,
                       float* __restrict__ hWa, float* __restrict__ hWh,
                       float* __restrict__ hWhh, float* __restrict__ yinp,
                       float* __restrict__ yin, float* __restrict__ nz,
                       float* __restrict__ scores) {
  int bx = blockIdx.x, t = threadIdx.x;
  if (bx < 6144) {
    size_t i = ((size_t)bx * 256 + t) * 8;
    const float* src = (i < 8388608) ? (ex + i) : (ec + (i - 8388608));
    float4 f0 = *(const float4*)src;
    float4 f1 = *(const float4*)(src + 4);
    *(short8*)&encb[i] = cvt8(f0, f1);
  } else if (bx < 6400) {
    __shared__ float tile[64][65];
    int bb = bx - 6144;
    int bi = bb >> 4, bj = bb & 15;
    int c = t & 63, rq = t >> 6;
#pragma unroll
    for (int rr = 0; rr < 16; rr++) {
      int kl = rr * 4 + rq;
      tile[kl][c] = Wa[(size_t)(1024 + bi * 64 + kl) * 1024 + bj * 64 + c];
    }
    __syncthreads();
#pragma unroll
    for (int rr = 0; rr < 16; rr++) {
      int nl = rr * 4 + rq;
      WaT[(size_t)(bj * 64 + nl) * 1024 + bi * 64 + c] = f2bf(tile[c][nl]);
    }
  } else if (bx < 6432) {
    __shared__ float red[4][64];
    int bb = bx - 6400;
    int ol = t & 63, kc = t >> 6;
    int o = bb * 64 + ol;
    const float* W = (o < 1024) ? Wa : Wh;
    int col = (o < 1024) ? o : (o - 1024);
    float acc = 0.f;
#pragma unroll 4
    for (int k = kc * 256; k < kc * 256 + 256; k++) acc += hid[k] * W[(size_t)k * 1024 + col];
    red[kc][ol] = acc;
    __syncthreads();
    if (t < 64) {
      int oo = bb * 64 + t;
      float s = red[0][t] + red[1][t] + red[2][t] + red[3][t];
      if (oo < 1024) hWa[oo] = s + ba[oo];
      else hWh[oo - 1024] = s + bh[oo - 1024];
    }
  } else if (bx < 6496) {
    __shared__ float red[4][64];
    int bb = bx - 6432;
    int ol = t & 63, kc = t >> 6;
    int o = bb * 64 + ol;
    float acc = 0.f;
#pragma unroll 4
    for (int k = kc * 256; k < kc * 256 + 256; k++) acc += hid[k] * Whh[(size_t)k * 4096 + o];
    red[kc][ol] = acc;
    __syncthreads();
    if (t < 64) {
      int oo = bb * 64 + t;
      hWhh[oo] = red[0][t] + red[1][t] + red[2][t] + red[3][t] + bih[oo] + bhh[oo];
    }
  } else if (bx == 6496) {
    int id = idx[0];
    for (int k = t; k < 300; k += 256) {
      yinp[k] = embed[(size_t)id * 300 + k];
      yin[k] = by[k];
    }
    for (int k = t; k < 12288; k += 256) scores[k] = 0.f;
  } else {
    __shared__ float r2[4];
    int j = bx - 6497;
    float a = 0.f;
    for (int k = t; k < 32768; k += 256) a += pmat[(size_t)j * 32768 + k];
    a = wred_sum(a);
    if ((t & 63) == 0) r2[t >> 6] = a;
    __syncthreads();
    if (t == 0) nz[j] = r2[0] + r2[1] + r2[2] + r2[3];
  }
}

// ---------------- K2: scores GEMM, BM=128 BN=256 BK=64, XOR-swizzled LDS; atomicAdd epilogue
__global__ __launch_bounds__(256, 2) void k_scores_gemm(
    const unsigned short* __restrict__ encb, const unsigned short* __restrict__ WaT,
    const float* __restrict__ hWa, const float* __restrict__ va,
    float* __restrict__ scores) {
  __shared__ __align__(16) unsigned short As[128 * 64];
  __shared__ __align__(16) unsigned short Bs[256 * 64];
  __shared__ float red[2][128];
  int mtile = blockIdx.x, ntile = blockIdx.y;
  int t = threadIdx.x, lane = t & 63, wid = t >> 6;
  int wr = wid >> 1, wc = wid & 1;
  int l15 = lane & 15, lg = lane >> 4;
  int r0 = mtile * 128;

  f32x4 acc[4][8];
#pragma unroll
  for (int m = 0; m < 4; m++)
#pragma unroll
    for (int n = 0; n < 8; n++) acc[m][n] = (f32x4){0.f, 0.f, 0.f, 0.f};

  for (int kt = 0; kt < 1024; kt += 64) {
#pragma unroll
    for (int p = 0; p < 4; p++) {
      int c = p * 256 + t;
      int row = c >> 3, slot = c & 7;
      const unsigned short* g =
          encb + (size_t)(r0 + row) * 1024 + kt + ((slot ^ (row & 7)) * 8);
      gl2lds16(g, &As[c * 8]);
    }
#pragma unroll
    for (int p = 0; p < 8; p++) {
      int c = p * 256 + t;
      int row = c >> 3, slot = c & 7;
      const unsigned short* g =
          WaT + (size_t)(ntile * 256 + row) * 1024 + kt + ((slot ^ (row & 7)) * 8);
      gl2lds16(g, &Bs[c * 8]);
    }
    __syncthreads();
#pragma unroll
    for (int ks = 0; ks < 2; ks++) {
      int q = ks * 4 + lg;
      short8 a[4];
#pragma unroll
      for (int m = 0; m < 4; m++) {
        int row = wr * 64 + m * 16 + l15;
        a[m] = *(const short8*)&As[row * 64 + ((q ^ (row & 7)) * 8)];
      }
#pragma unroll
      for (int n = 0; n < 8; n++) {
        int nr = wc * 128 + n * 16 + l15;
        short8 b = *(const short8*)&Bs[nr * 64 + ((q ^ (nr & 7)) * 8)];
#pragma unroll
        for (int m = 0; m < 4; m++)
          acc[m][n] = __builtin_amdgcn_mfma_f32_16x16x32_bf16(a[m], b, acc[m][n], 0, 0, 0);
      }
    }
    __syncthreads();
  }

  float vva[8], hba[8];
#pragma unroll
  for (int n = 0; n < 8; n++) {
    int col = ntile * 256 + wc * 128 + n * 16 + l15;
    vva[n] = va[col];
    hba[n] = hWa[col];
  }
#pragma unroll
  for (int m = 0; m < 4; m++) {
#pragma unroll
    for (int j = 0; j < 4; j++) {
      float p = 0.f;
#pragma unroll
      for (int n = 0; n < 8; n++) p += vva[n] * tanhf(acc[m][n][j] + hba[n]);
#pragma unroll
      for (int o = 1; o < 16; o <<= 1) p += __shfl_xor(p, o, 64);
      if (l15 == 0) red[wc][wr * 64 + m * 16 + lg * 4 + j] = p;
    }
  }
  __syncthreads();
  if (t < 128) atomicAdd(&scores[r0 + t], red[0][t] + red[1][t]);
}

// ---------------- K3: weighted-sum partials; per-block redundant segment softmax stats
__global__ void k_weighted_part(const unsigned short* __restrict__ encb,
                                const float* __restrict__ scores,
                                float* __restrict__ partw) {
  __shared__ float r4m[4], r4z[4];
  __shared__ float wrow[64];
  int b = blockIdx.x, colq = blockIdx.y, t = threadIdx.x;
  int seg = (b >= 128) ? 1 : 0;
  int sbase = seg ? 8192 : 0;
  int len = seg ? 4096 : 8192;
  int rb = (seg ? (b - 128) : b) * 64;

  // segment stats (redundant per block)
  float sv[32];
  float m = -1e30f;
#pragma unroll
  for (int q = 0; q < 32; q++) {
    int r = q * 256 + t;
    sv[q] = (r < len) ? scores[sbase + r] : -1e30f;
    m = fmaxf(m, sv[q]);
  }
  m = wred_max(m);
  if ((t & 63) == 0) r4m[t >> 6] = m;
  __syncthreads();
  m = fmaxf(fmaxf(r4m[0], r4m[1]), fmaxf(r4m[2], r4m[3]));
  float z = 0.f;
#pragma unroll
  for (int q = 0; q < 32; q++) {
    int r = q * 256 + t;
    if (r < len) z += expf(sv[q] - m);
  }
  z = wred_sum(z);
  if ((t & 63) == 0) r4z[t >> 6] = z;
  __syncthreads();
  z = r4z[0] + r4z[1] + r4z[2] + r4z[3];
  float invz = 1.0f / z;
  if (t < 64) wrow[t] = expf(scores[sbase + rb + t] - m) * invz;
  __syncthreads();

  int c2 = colq * 512 + 2 * t;
  float a0 = 0.f, a1 = 0.f;
  size_t rowbase = (size_t)b * 64 * 1024;
#pragma unroll 8
  for (int r = 0; r < 64; r++) {
    unsigned u = *(const unsigned*)&encb[rowbase + (size_t)r * 1024 + c2];
    float w = wrow[r];
    a0 += w * __uint_as_float(u << 16);
    a1 += w * __uint_as_float(u & 0xffff0000u);
  }
  float2 o; o.x = a0; o.y = a1;
  *(float2*)&partw[(size_t)b * 1024 + c2] = o;
}

// ---------------- K4 (combine folded in): wgP[kq][o] = wxc[kq-slice] @ Wg-slice
__global__ void k_weighted_gemv(const float* __restrict__ partw, const float* __restrict__ Wg,
                                float* __restrict__ wgP) {
  __shared__ float wxcL[64];
  int oq = blockIdx.x, kq = blockIdx.y, t = threadIdx.x;
  if (t < 64) {
    float s = 0.f;
    if (kq < 16) {
      int d = kq * 64 + t;
#pragma unroll 8
      for (int b = 0; b < 128; b++) s += partw[(size_t)b * 1024 + d];
    } else {
      int d = (kq - 16) * 64 + t;
#pragma unroll 8
      for (int b = 128; b < 192; b++) s += partw[(size_t)b * 1024 + d];
    }
    wxcL[t] = s;
  }
  __syncthreads();
  int o = oq * 256 + t;
  int k0 = kq * 64;
  float acc = 0.f;
#pragma unroll 8
  for (int j = 0; j < 64; j++) acc += wxcL[j] * Wg[(size_t)(k0 + j) * 1024 + o];
  wgP[(size_t)kq * 1024 + o] = acc;
}

// ---------------- K5 merged: block0 = wgfin+charsel+writes ; blocks 1..64 = pp partials
__global__ void k_wgfin_pp(const float* __restrict__ wgP, const float* __restrict__ bg,
                           const float* __restrict__ yinp, const float* __restrict__ hid,
                           const float* __restrict__ Wchar, const float* __restrict__ bchar,
                           const float* __restrict__ nz, float* __restrict__ weighted,
                           int* __restrict__ sel, const float* __restrict__ pmat,
                           const float* __restrict__ Wp, float* __restrict__ ppP,
                           float* __restrict__ dout) {
  __shared__ float WL[1024];
  __shared__ float red6[4][6];
  __shared__ int ssel;
  int bid = blockIdx.x, t = threadIdx.x;
  for (int q = 0; q < 4; q++) {
    int d = t + q * 256;
    float s = bg[d];
#pragma unroll 8
    for (int b = 0; b < 32; b++) s += wgP[(size_t)b * 1024 + d];
    WL[d] = s;
    if (bid == 0) { weighted[d] = s; dout[OUT_W + d] = s; }
  }
  __syncthreads();
  float p[6] = {0.f, 0.f, 0.f, 0.f, 0.f, 0.f};
  for (int k = t; k < 2348; k += 256) {
    float xv = (k < 300) ? yinp[k] : (k < 1324 ? hid[k - 300] : WL[k - 1324]);
#pragma unroll
    for (int ch = 0; ch < 6; ch++) p[ch] += xv * Wchar[k * 6 + ch];
  }
#pragma unroll
  for (int ch = 0; ch < 6; ch++) {
    float v = wred_sum(p[ch]);
    if ((t & 63) == 0) red6[t >> 6][ch] = v;
  }
  __syncthreads();
  if (t == 0) {
    float best = -1e30f; int si = 0;
    for (int ch = 0; ch < 6; ch++) {
      float lgt = red6[0][ch] + red6[1][ch] + red6[2][ch] + red6[3][ch] + bchar[ch];
      if (nz[ch] != 0.0f && lgt > best) { best = lgt; si = ch; }
    }
    ssel = si;
    if (bid == 0) *sel = si;
  }
  __syncthreads();
  if (bid == 0) return;
  __shared__ float sr[32][64];
  int u = bid - 1;
  int oq = u >> 4, kq = u & 15;
  int row0 = ssel * 32;
  int k0 = kq * 64;
#pragma unroll
  for (int j = 0; j < 8; j++) {
    int idx2 = t + j * 256;
    int i = idx2 >> 6, kk = idx2 & 63;
    sr[i][kk] = pmat[(size_t)(row0 + i) * 1024 + k0 + kk];
  }
  __syncthreads();
  int o = oq * 256 + t;
  float acc[32];
#pragma unroll
  for (int i = 0; i < 32; i++) acc[i] = 0.f;
  for (int k = 0; k < 64; k++) {
    float w = Wp[(size_t)(k0 + k) * 1024 + o];
#pragma unroll
    for (int i = 0; i < 32; i++) acc[i] += sr[i][k] * w;
  }
#pragma unroll
  for (int i = 0; i < 32; i++) ppP[(size_t)kq * 32768 + i * 1024 + o] = acc[i];
}

// ---------------- K6b: pp[i] = sum ppP + bp ; att[i] = vv . tanh(hWh+pp)
__global__ void k_ppfin_att(const float* __restrict__ ppP, const float* __restrict__ bp,
                            const float* __restrict__ hWh, const float* __restrict__ vv,
                            float* __restrict__ attb) {
  __shared__ float r4[4];
  int i = blockIdx.x, t = threadIdx.x;
  float pt = 0.f;
  if (i < 32) {
    for (int q = 0; q < 4; q++) {
      int d = t + q * 256;
      float s = bp[d];
#pragma unroll
      for (int kq = 0; kq < 16; kq++) s += ppP[(size_t)kq * 32768 + i * 1024 + d];
      pt += vv[d] * tanhf(hWh[d] + s);
    }
  } else {
    for (int q = 0; q < 4; q++) {
      int d = t + q * 256;
      pt += vv[d] * tanhf(hWh[d] + bp[d]);
    }
  }
  pt = wred_sum(pt);
  if ((t & 63) == 0) r4[t >> 6] = pt;
  __syncthreads();
  if (t == 0) attb[i] = r4[0] + r4[1] + r4[2] + r4[3];
}

// ---------------- K7a: softmax(att) ; p_attn on demand ; y_in += partial (atomic)
__global__ void k_pattn_yin(const float* __restrict__ attb, const float* __restrict__ pmat,
                            const int* __restrict__ sel, const float* __restrict__ yinp,
                            const float* __restrict__ weighted, const float* __restrict__ Wy,
                            float* __restrict__ yin, float* __restrict__ dout) {
  __shared__ float sc32[32];
  __shared__ float XLb[74];
  int b = blockIdx.x, t = threadIdx.x;
  if (t == 0) {
    float az = attb[32];
    float m = az;
#pragma unroll
    for (int i = 0; i < 32; i++) m = fmaxf(m, attb[i]);
    float Z = 160.0f * expf(az - m);
#pragma unroll
    for (int i = 0; i < 32; i++) Z += expf(attb[i] - m);
#pragma unroll
    for (int i = 0; i < 32; i++) sc32[i] = expf(attb[i] - m) / Z;
  }
  __syncthreads();
  if (b == 0 && t < 32) dout[OUT_PS + t] = sc32[t];
  int base = b * 74;
  int len = 2348 - base; if (len > 74) len = 74;
  int srow0 = (*sel) * 32;
  if (t < len) {
    int k = base + t;
    float xv;
    if (k < 300) xv = yinp[k];
    else if (k < 1324) xv = weighted[k - 300];
    else {
      int d = k - 1324;
      float acc = 0.f;
#pragma unroll
      for (int i = 0; i < 32; i++) acc += sc32[i] * pmat[(size_t)(srow0 + i) * 1024 + d];
      xv = acc;
    }
    XLb[t] = xv;
  }
  __syncthreads();
  if (t < 300) {
    float acc = 0.f;
    for (int j = 0; j < len; j++) acc += XLb[j] * Wy[(size_t)(base + j) * 300 + t];
    atomicAdd(&yin[t], acc);
  }
}

// ---------------- K7b: gatesP[kq] = y_in@Wih partials only (k-split 4); Whh part precomputed
__global__ void k_gates_part(const float* __restrict__ yin, const float* __restrict__ Wih,
                             float* __restrict__ gatesP) {
  __shared__ float YLb[75];
  __shared__ float red[4][64];
  int bx = blockIdx.x, kq = blockIdx.y, t = threadIdx.x;
  int k0i = kq * 75;
  if (t < 75) YLb[t] = yin[k0i + t];
  __syncthreads();
  int ol = t & 63, kc = t >> 6;
  int o = bx * 64 + ol;
  float acc = 0.f;
  for (int k = k0i + kc; k < k0i + 75; k += 4) acc += YLb[k - k0i] * Wih[(size_t)k * 4096 + o];
  red[kc][ol] = acc;
  __syncthreads();
  if (t < 64) {
    int oo = bx * 64 + t;
    gatesP[(size_t)kq * 4096 + oo] = red[0][t] + red[1][t] + red[2][t] + red[3][t];
  }
}

// ---------------- K8 (LSTM folded in): h1 32-slice from gatesP+hWhh, then float4 logits partials
__global__ __launch_bounds__(256) void k_out_gemv(const float* __restrict__ gatesP,
                                                  const float* __restrict__ hWhh,
                                                  const float* __restrict__ c0,
                                                  const float* __restrict__ Wout,
                                                  float* __restrict__ partK,
                                                  float* __restrict__ dout) {
  __shared__ float hh[32];
  int ks = blockIdx.x, cb = blockIdx.y, t = threadIdx.x;
  if (t < 32) {
    int d = ks * 32 + t;
    float gi = hWhh[d];
    float gf = hWhh[1024 + d];
    float gg = hWhh[2048 + d];
    float go = hWhh[3072 + d];
#pragma unroll
    for (int kq = 0; kq < 4; kq++) {
      const float* g = gatesP + (size_t)kq * 4096;
      gi += g[d]; gf += g[1024 + d]; gg += g[2048 + d]; go += g[3072 + d];
    }
    float c1 = sigmoidf(gf) * c0[d] + sigmoidf(gi) * tanhf(gg);
    float h1 = sigmoidf(go) * tanhf(c1);
    hh[t] = h1;
    if (cb == 0) { dout[OUT_H1 + d] = h1; dout[OUT_C1 + d] = c1; }
  }
  __syncthreads();
  const float* W = Wout + (size_t)ks * 32 * 50257;
  int c4 = cb * 1024 + t * 4;
  if (c4 + 4 <= 50257) {
    f32x4 a = (f32x4){0.f, 0.f, 0.f, 0.f};
#pragma unroll 4
    for (int k = 0; k < 32; k++) {
      f32x4u w = *(const f32x4u*)&W[(size_t)k * 50257 + c4];
      float h = hh[k];
      a[0] += h * w[0]; a[1] += h * w[1]; a[2] += h * w[2]; a[3] += h * w[3];
    }
    *(f32x4*)&partK[(size_t)ks * PKS + c4] = a;
  } else if (c4 < 50257) {
    for (int c = c4; c < 50257; c++) {
      float a = 0.f;
#pragma unroll 8
      for (int k = 0; k < 32; k++) a += hh[k] * W[(size_t)k * 50257 + c];
      partK[(size_t)ks * PKS + c] = a;
    }
  }
}

// ---------------- K9a: logits = sum partials + bout ; per-block max & sumexp (197 blocks)
__global__ void k_logits_stats(const float* __restrict__ partK, const float* __restrict__ bout,
                               float* __restrict__ logits, float* __restrict__ bstat) {
  __shared__ float r4[4];
  int bx = blockIdx.x, t = threadIdx.x;
  int c = bx * 256 + t;
  float v = -1e30f;
  if (c < 50257) {
    v = bout[c];
#pragma unroll
    for (int ks = 0; ks < 32; ks++) v += partK[(size_t)ks * PKS + c];
    logits[c] = v;
  }
  float m = wred_max(v);
  if ((t & 63) == 0) r4[t >> 6] = m;
  __syncthreads();
  m = fmaxf(fmaxf(r4[0], r4[1]), fmaxf(r4[2], r4[3]));
  __syncthreads();
  float z = (c < 50257) ? expf(v - m) : 0.f;
  z = wred_sum(z);
  if ((t & 63) == 0) r4[t >> 6] = z;
  __syncthreads();
  if (t == 0) { bstat[bx] = m; bstat[256 + bx] = r4[0] + r4[1] + r4[2] + r4[3]; }
}

// ---------------- K9c: merge stats (redundant per block) + out = exp(logit - M)/Z
__global__ void k_out_final(const float* __restrict__ bstat, const float* __restrict__ logits,
                            float* __restrict__ dout) {
  __shared__ float r4m[4], r4z[4];
  int bx = blockIdx.x, t = threadIdx.x;
  float mv = (t < 197) ? bstat[t] : -1e30f;
  float m = wred_max(mv);
  if ((t & 63) == 0) r4m[t >> 6] = m;
  __syncthreads();
  m = fmaxf(fmaxf(r4m[0], r4m[1]), fmaxf(r4m[2], r4m[3]));
  __syncthreads();
  float zv = (t < 197) ? bstat[256 + t] * expf(bstat[t] - m) : 0.f;
  float z = wred_sum(zv);
  if ((t & 63) == 0) r4z[t >> 6] = z;
  __syncthreads();
  float Z = r4z[0] + r4z[1] + r4z[2] + r4z[3];
  int c = bx * 256 + t;
  if (c < 50257) dout[c] = expf(logits[c] - m) / Z;
}

extern "C" void kernel_launch(void* const* d_in, const int* in_sizes, int n_in,
                              void* d_out, int out_size, void* d_ws, size_t ws_size,
                              hipStream_t stream) {
  (void)in_sizes; (void)n_in; (void)out_size; (void)ws_size;
  const int*   idx   = (const int*)  d_in[0];
  const float* ex    = (const float*)d_in[1];
  const float* ec    = (const float*)d_in[2];
  const float* pmat  = (const float*)d_in[3];
  const float* hid   = (const float*)d_in[4];
  const float* c0    = (const float*)d_in[5];
  const float* embed = (const float*)d_in[8];
  const float* Wa    = (const float*)d_in[9];
  const float* ba    = (const float*)d_in[10];
  const float* va    = (const float*)d_in[11];
  const float* Wg    = (const float*)d_in[12];
  const float* bg    = (const float*)d_in[13];
  const float* Wchar = (const float*)d_in[14];
  const float* bchar = (const float*)d_in[15];
  const float* Wp    = (const float*)d_in[16];
  const float* bp    = (const float*)d_in[17];
  const float* Wh    = (const float*)d_in[18];
  const float* bh    = (const float*)d_in[19];
  const float* vv    = (const float*)d_in[20];
  const float* Wy    = (const float*)d_in[21];
  const float* by    = (const float*)d_in[22];
  const float* Wih   = (const float*)d_in[23];
  const float* Whh   = (const float*)d_in[24];
  const float* bih   = (const float*)d_in[25];
  const float* bhh   = (const float*)d_in[26];
  const float* Wout  = (const float*)d_in[27];
  const float* bout  = (const float*)d_in[28];
  float* out = (float*)d_out;

  char* ws = (char*)d_ws;
  // Phase-1 zone (dead before k_out_gemv):
  unsigned short* encb = (unsigned short*)(ws + 0);         // 25,165,824
  unsigned short* WaT  = (unsigned short*)(ws + 25165824);  //  2,097,152 -> 27,262,976
  float* scores   = (float*)(ws + 27656192);                //     49,152 -> 27,705,344
  float* partw    = (float*)(ws + 27705856);                //    786,432 -> 28,492,288
  float* wgP      = (float*)(ws + 28492288);                //    131,072 -> 28,623,360
  // Phase-2 zone (overlaps phase-1 only):
  float* partK    = (float*)(ws + 0);                       //  6,433,280 (32 x 50260 x 4)
  float* logits   = (float*)(ws + 6433280);                 //    201,152 -> 6,634,432
  // Persistent zone:
  float* ppP      = (float*)(ws + 28623360);                //  2,097,152 -> 30,720,512
  float* attb     = (float*)(ws + 30720512);                //        256
  float* yin      = (float*)(ws + 30720768);                //      1,536
  float* gatesP   = (float*)(ws + 30759424);                //     65,536
  float* hWa      = (float*)(ws + 30890496);                //      4,096
  float* hWh      = (float*)(ws + 30894592);                //      4,096
  float* yinp     = (float*)(ws + 30898688);                //      1,536
  float* nz       = (float*)(ws + 30900224);                //        256
  float* weighted = (float*)(ws + 30900480);                //      4,096
  int*   sel      = (int*)  (ws + 30904576);                //        256
  float* bstat    = (float*)(ws + 30904832);                //      2,048
  float* hWhh     = (float*)(ws + 30906880);                //     16,384 -> 30,923,264 total

  k_prep<<<6503, 256, 0, stream>>>(ex, ec, Wa, ba, Wh, bh, Whh, bih, bhh, hid, embed, idx,
                                   pmat, by, encb, WaT, hWa, hWh, hWhh, yinp, yin, nz, scores);
  k_scores_gemm<<<dim3(96, 4), 256, 0, stream>>>(encb, WaT, hWa, va, scores);
  k_weighted_part<<<dim3(192, 2), 256, 0, stream>>>(encb, scores, partw);
  k_weighted_gemv<<<dim3(4, 32), 256, 0, stream>>>(partw, Wg, wgP);
  k_wgfin_pp<<<65, 256, 0, stream>>>(wgP, bg, yinp, hid, Wchar, bchar, nz, weighted, sel,
                                     pmat, Wp, ppP, out);
  k_ppfin_att<<<33, 256, 0, stream>>>(ppP, bp, hWh, vv, attb);
  k_pattn_yin<<<32, 320, 0, stream>>>(attb, pmat, sel, yinp, weighted, Wy, yin, out);
  k_gates_part<<<dim3(64, 4), 256, 0, stream>>>(yin, Wih, gatesP);
  k_out_gemv<<<dim3(32, 50), 256, 0, stream>>>(gatesP, hWhh, c0, Wout, partK, out);
  k_logits_stats<<<197, 256, 0, stream>>>(partK, bout, logits, bstat);
  k_out_final<<<197, 256, 0, stream>>>(bstat, logits, out);
}